// Round 1
// baseline (125.710 us; speedup 1.0000x reference)
//
#include <hip/hip_runtime.h>
#include <hip/hip_bf16.h>
#include <stdint.h>

// KAN layer: out[b,o] = sum_{i,k} basis(tanh(x[b,i]))[k] * coeffs[o,i,k]
// GEMM M=8192, N=512, K=4096.  cvt coeffs->Bt bf16 (ws) ; basis(x)->A (ws) ;
// gemm(A,Bt)->out.
// R7 post-mortem: 818 TF, MfmaUtil 31%, bank-conflict 0, HBM 1.6 TB/s ->
// latency-bound: 1-deep prefetch + implicit vmcnt(0) drain at __syncthreads
// can't cover loaded HBM latency (~2kcy with 256 CUs streaming A).
// R8: T3/T4 counted-vmcnt deep pipeline. BK 64->32 (buf 16KB), 4 buffers per
// K-group (same 128KB LDS), prologue stages 3 tiles, steady state issues
// tile it+3 then s_waitcnt vmcnt(12) (tiles it+1..it+3 in flight ~2.1kcy
// cover), raw s_barrier x2 per iter (no full drain in main loop).
// LDS swizzle for 4-chunk rows: 2 rows/128B line, slot=((r&1)*4+c)^((r>>1)&7);
// per-quad frag reads hit all 8 slots exactly 2x per 16 lanes (2-way = free).
// Inverse swizzle applied to global source of global_load_lds (rule #21).

#define M_TOTAL 8192
#define N_DIM   512
#define K_DIM   4096
#define BM 128
#define BN 128
#define BK 32
#define NT_HALF 64          // K-tiles per K-group (2048/32)
#define PF 3                // prefetch depth (tiles in flight)
#define BUF_SZ 16384        // one buffer: A 8KB + B 8KB
#define GRP_LDS 65536       // per-group arena: 4 buffers

typedef __attribute__((ext_vector_type(8))) short short8;   // 8 x bf16
typedef __attribute__((ext_vector_type(4))) float f32x4;

typedef const __attribute__((address_space(1))) uint32_t ga_u32;
typedef __attribute__((address_space(3))) uint32_t ls_u32;

__device__ __forceinline__ void gload_lds16(const void* g, void* l) {
  // async global->LDS, 16B/lane; LDS dest = wave-uniform base + lane*16
  __builtin_amdgcn_global_load_lds((ga_u32*)(uintptr_t)g,
                                   (ls_u32*)(uint32_t)(uintptr_t)l, 16, 0, 0);
}

__device__ __forceinline__ uint32_t f2bf(float f) {
  uint32_t u = __builtin_bit_cast(uint32_t, f);
  return (u + 0x7FFFu + ((u >> 16) & 1u)) >> 16;
}

// cardinal cubic B-spline on uniform knots h=2/11; t=tanh(x) in (-1,1).
// 8 basis slots as 4xu32 packed bf16: w0..w3 land at slots c-3..c, rest 0.
__device__ __forceinline__ void basis_slots(float xv, uint32_t o[4]) {
  xv = fminf(15.f, fmaxf(-15.f, xv));
  float e  = __expf(2.0f * xv);
  float t  = (e - 1.0f) * __builtin_amdgcn_rcpf(e + 1.0f);
  float uf = (t + 1.0f) * 5.5f;            // /h
  int   c  = (int)uf;  c = c > 10 ? 10 : c;
  float u  = uf - (float)c;
  float u2 = u * u, u3 = u2 * u, om = 1.0f - u;
  float w0 = om * om * om * (1.0f / 6.0f);
  float w1 = (3.0f * u3 - 6.0f * u2 + 4.0f) * (1.0f / 6.0f);
  float w2 = (-3.0f * u3 + 3.0f * u2 + 3.0f * u + 1.0f) * (1.0f / 6.0f);
  float w3 = u3 * (1.0f / 6.0f);
  uint32_t p01 = f2bf(w0) | (f2bf(w1) << 16);
  uint32_t p23 = f2bf(w2) | (f2bf(w3) << 16);
  uint64_t W = (uint64_t)p01 | ((uint64_t)p23 << 32);
  int d = c - 3;                            // slot of w0, in [-3, 7]
  uint64_t lo = (d < 0) ? (W >> ((-d) * 16))
              : ((d < 4) ? (W << (d * 16)) : 0ull);
  uint64_t hi = (d <= 0) ? 0ull
              : ((d < 4) ? (W >> ((4 - d) * 16)) : (W << ((d - 4) * 16)));
  o[0] = (uint32_t)lo; o[1] = (uint32_t)(lo >> 32);
  o[2] = (uint32_t)hi; o[3] = (uint32_t)(hi >> 32);
}

// ---------------- basis kernel: one (b,i) per thread, 16B store --------------
__global__ __launch_bounds__(256) void basis_kernel(const float* __restrict__ x,
                                                    __hip_bfloat16* __restrict__ A,
                                                    int total) {
  int idx = blockIdx.x * 256 + threadIdx.x;
  if (idx >= total) return;
  uint32_t o[4];
  basis_slots(x[idx], o);
  reinterpret_cast<int4*>(A)[idx] = make_int4(o[0], o[1], o[2], o[3]);
}

// ---------------- coeff cast: [512][512][8] fp32 -> bf16 (== B^T[512][4096]) --
__global__ __launch_bounds__(256) void cvt_kernel(const float* __restrict__ c,
                                                  __hip_bfloat16* __restrict__ Bt,
                                                  int total8) {
  int idx = blockIdx.x * 256 + threadIdx.x;
  if (idx >= total8) return;
  const float4* cp = reinterpret_cast<const float4*>(c) + (size_t)idx * 2;
  float4 a = cp[0], b = cp[1];
  union { unsigned short us[8]; int4 v; } pk;
  pk.us[0] = (unsigned short)f2bf(a.x); pk.us[1] = (unsigned short)f2bf(a.y);
  pk.us[2] = (unsigned short)f2bf(a.z); pk.us[3] = (unsigned short)f2bf(a.w);
  pk.us[4] = (unsigned short)f2bf(b.x); pk.us[5] = (unsigned short)f2bf(b.y);
  pk.us[6] = (unsigned short)f2bf(b.z); pk.us[7] = (unsigned short)f2bf(b.w);
  reinterpret_cast<int4*>(Bt)[idx] = pk.v;
}

// ---------------- GEMM: C[m,n] = sum_k A[m,k]*Bt[n,k] ------------------------
// 512 thr = 8 waves: kgrp = wid>>2 (K-half), 2x2 waves of 64x64 per group.
__global__ __launch_bounds__(512) void gemm_kernel(
    const __hip_bfloat16* __restrict__ A,   // [8192][4096]
    const __hip_bfloat16* __restrict__ Bt,  // [512][4096]
    float* __restrict__ C) {                // [8192][512]
  __shared__ char lds[2 * GRP_LDS];         // 128 KB

  const int tid   = threadIdx.x;
  const int wid   = tid >> 6;               // 0..7
  const int lane  = tid & 63;
  const int quad  = lane >> 4;
  const int l16   = lane & 15;
  const int kgrp  = wid >> 2;               // 0..1: K-half
  const int w2    = wid & 3;
  const int waveM = w2 >> 1, waveN = w2 & 1;
  const int tg    = tid & 255;              // thread-in-group

  // XCD decode: each XCD owns 8 M-stripes x all 4 N-tiles; Bt (4MB) stays
  // L2-resident per XCD, A-stripes stream through once.
  const int b  = blockIdx.x;
  const int q  = b >> 3;                    // 0..31
  const int mt = (b & 7) * 8 + (q >> 2);    // 0..63
  const int nt = q & 3;                     // 0..3
  const int m0 = mt * BM;
  const int n0 = nt * BN;

  char* grp = lds + kgrp * GRP_LDS;

  // staging: linear slot s (phys) -> logical (row r, chunk c):
  //   L = s>>3, sl = s&7, u = sl ^ (L&7), r = 2L + (u>>2), c = u&3
  uint32_t aGlob[2], bGlob[2], sOff[2];
#pragma unroll
  for (int t = 0; t < 2; ++t) {
    int s = t * 256 + tg;                   // 0..511
    int L = s >> 3, sl = s & 7;
    int u = sl ^ (L & 7);
    int r = L * 2 + (u >> 2);
    int c = u & 3;
    sOff[t]  = (uint32_t)s * 16u;
    aGlob[t] = (uint32_t)(m0 + r) * K_DIM + (uint32_t)c * 8u
             + (uint32_t)kgrp * 2048u;
    bGlob[t] = (uint32_t)(n0 + r) * K_DIM + (uint32_t)c * 8u
             + (uint32_t)kgrp * 2048u;
  }

  // fragment read offsets within a buffer (A at +0, B at +8KB):
  //   row r, chunk quad -> L=r>>1, sl=((r&1)*4+quad)^(L&7), byte=(L*8+sl)*16
  uint32_t aOff[4], bOff[4];
#pragma unroll
  for (int mi = 0; mi < 4; ++mi) {
    int r = waveM * 64 + mi * 16 + l16;
    int L = r >> 1;
    int sl = (((r & 1) << 2) | quad) ^ (L & 7);
    aOff[mi] = (uint32_t)(L * 8 + sl) * 16u;
  }
#pragma unroll
  for (int ni = 0; ni < 4; ++ni) {
    int r = waveN * 64 + ni * 16 + l16;
    int L = r >> 1;
    int sl = (((r & 1) << 2) | quad) ^ (L & 7);
    bOff[ni] = 8192u + (uint32_t)(L * 8 + sl) * 16u;
  }

  f32x4 acc[4][4];
#pragma unroll
  for (int mi = 0; mi < 4; ++mi)
#pragma unroll
    for (int ni = 0; ni < 4; ++ni)
      acc[mi][ni] = (f32x4){0.f, 0.f, 0.f, 0.f};

#define STAGE(IT) do {                                                        \
    char* bufn_ = grp + (((IT) & 3) * BUF_SZ);                                \
    uint32_t kt_ = (uint32_t)(IT) * BK;                                       \
    _Pragma("unroll")                                                         \
    for (int t = 0; t < 2; ++t) {                                             \
      gload_lds16(A + aGlob[t] + kt_, bufn_ + sOff[t]);                       \
      gload_lds16(Bt + bGlob[t] + kt_, bufn_ + 8192 + sOff[t]);               \
    }                                                                         \
  } while (0)

  // prologue: stage tiles 0..PF-1 (12 loads/thread outstanding)
#pragma unroll
  for (int p = 0; p < PF; ++p) STAGE(p);

  for (int it = 0; it < NT_HALF; ++it) {
    char* bufc = grp + (it & 3) * BUF_SZ;
    // issue tile it+PF, then wait ONLY for tile it (counted vmcnt, T4):
    // outstanding after issue = 4 loads x tiles {it+1..it+PF} = 12.
    if (it + 3 < NT_HALF) {
      STAGE(it + 3);
      asm volatile("s_waitcnt vmcnt(12)" ::: "memory");
    } else if (it + 2 < NT_HALF) {
      asm volatile("s_waitcnt vmcnt(8)" ::: "memory");
    } else if (it + 1 < NT_HALF) {
      asm volatile("s_waitcnt vmcnt(4)" ::: "memory");
    } else {
      asm volatile("s_waitcnt vmcnt(0)" ::: "memory");
    }
    __builtin_amdgcn_s_barrier();           // all waves' tile-it loads landed

    short8 af[4], bf[4];
#pragma unroll
    for (int mi = 0; mi < 4; ++mi)
      af[mi] = *reinterpret_cast<const short8*>(bufc + aOff[mi]);
#pragma unroll
    for (int ni = 0; ni < 4; ++ni)
      bf[ni] = *reinterpret_cast<const short8*>(bufc + bOff[ni]);
#pragma unroll
    for (int mi = 0; mi < 4; ++mi)
#pragma unroll
      for (int ni = 0; ni < 4; ++ni)
        acc[mi][ni] = __builtin_amdgcn_mfma_f32_16x16x32_bf16(
            af[mi], bf[ni], acc[mi][ni], 0, 0, 0);

    __builtin_amdgcn_s_barrier();           // frees buf[(it)&3] for stage it+4
  }
#undef STAGE

  // split-K pair reduction: group 1 parks partials, group 0 sums + stores
  __syncthreads();
  if (kgrp == 1) {
#pragma unroll
    for (int mi = 0; mi < 4; ++mi)
#pragma unroll
      for (int ni = 0; ni < 4; ++ni) {
        int f = mi * 4 + ni;
        *reinterpret_cast<f32x4*>(lds + w2 * 16384 + f * 1024 + lane * 16) =
            acc[mi][ni];
      }
  }
  __syncthreads();
  if (kgrp == 0) {
#pragma unroll
    for (int mi = 0; mi < 4; ++mi) {
#pragma unroll
      for (int ni = 0; ni < 4; ++ni) {
        int f = mi * 4 + ni;
        f32x4 other = *reinterpret_cast<f32x4*>(
            lds + w2 * 16384 + f * 1024 + lane * 16);
        f32x4 s = acc[mi][ni] + other;
        int col = n0 + waveN * 64 + ni * 16 + l16;
#pragma unroll
        for (int r = 0; r < 4; ++r) {
          int row = m0 + waveM * 64 + mi * 16 + quad * 4 + r;
          C[(size_t)row * N_DIM + col] = s[r];   // m89/m91 C/D layout
        }
      }
    }
  }
}

extern "C" void kernel_launch(void* const* d_in, const int* in_sizes, int n_in,
                              void* d_out, int out_size, void* d_ws, size_t ws_size,
                              hipStream_t stream) {
  const float* x    = (const float*)d_in[0];   // [8192,512]
  const float* coef = (const float*)d_in[1];   // [512,512,8]
  float* out = (float*)d_out;                  // [8192,512]

  __hip_bfloat16* Bt = (__hip_bfloat16*)d_ws;                       // 4 MB
  __hip_bfloat16* A  = (__hip_bfloat16*)((char*)d_ws + (size_t)4 * 1024 * 1024);
  // A = 64 MB; ws is ~268 MB (observed via harness poison fill), fits.

  const int total8 = N_DIM * K_DIM / 8;        // 262144
  cvt_kernel<<<(total8 + 255) / 256, 256, 0, stream>>>(coef, Bt, total8);

  const int total = M_TOTAL * 512;             // (b,i) pairs
  basis_kernel<<<total / 256, 256, 0, stream>>>(x, A, total);

  gemm_kernel<<<(M_TOTAL / BM) * (N_DIM / BN), 512, 0, stream>>>(A, Bt, out);
}

// Round 2
// 123.653 us; speedup vs baseline: 1.0166x; 1.0166x over previous
//
#include <hip/hip_runtime.h>
#include <hip/hip_bf16.h>
#include <stdint.h>

// KAN layer: out[b,o] = sum_{i,k} basis(tanh(x[b,i]))[k] * coeffs[o,i,k]
// GEMM M=8192, N=512, K=4096.  cvt coeffs->Bt bf16 (ws) ; fused gemm computes
// basis(x) on the fly while staging A into LDS.
// R8 post-mortem: BK=32 4-buf counted-vmcnt pipeline regressed (42->47.5us,
// 2x barrier count, 16 MFMA/phase too fine) -- matches m232's 8ph@128^2 null.
// R9: revert to the proven R7 skeleton (42us, 818TF) and delete the basis
// kernel instead: A[m,k] chunks (8 bf16 slots) are a pure function of one
// float x[m,i], so staging threads load x (float4 = 4 i's), run basis_slots,
// and ds_write_b128 the 4 chunks straight into the swizzled A slots.  Kills
// the 128MB A round-trip (basis kernel ~13us) at ~140 hidden VALU/thr/iter.
// B path (global_load_lds, pre-swizzled source) and sync structure unchanged.

#define M_TOTAL 8192
#define N_DIM   512
#define K_DIM   4096
#define BM 128
#define BN 128
#define BK 64
#define NT_HALF 32          // K-tiles per K-group (2048/64)
#define GRP_LDS 65536       // per-group arena: 2 buffers
#define BUF_HALF 32768      // one buffer: A 16KB + B 16KB

typedef __attribute__((ext_vector_type(8))) short short8;   // 8 x bf16
typedef __attribute__((ext_vector_type(4))) float f32x4;

typedef const __attribute__((address_space(1))) uint32_t ga_u32;
typedef __attribute__((address_space(3))) uint32_t ls_u32;

__device__ __forceinline__ void gload_lds16(const void* g, void* l) {
  // async global->LDS, 16B/lane; LDS dest = wave-uniform base + lane*16
  __builtin_amdgcn_global_load_lds((ga_u32*)(uintptr_t)g,
                                   (ls_u32*)(uint32_t)(uintptr_t)l, 16, 0, 0);
}

__device__ __forceinline__ uint32_t f2bf(float f) {
  uint32_t u = __builtin_bit_cast(uint32_t, f);
  return (u + 0x7FFFu + ((u >> 16) & 1u)) >> 16;
}

// cardinal cubic B-spline on uniform knots h=2/11; t=tanh(x) in (-1,1).
// 8 basis slots as 4xu32 packed bf16: w0..w3 land at slots c-3..c, rest 0.
__device__ __forceinline__ void basis_slots(float xv, uint32_t o[4]) {
  xv = fminf(15.f, fmaxf(-15.f, xv));
  float e  = __expf(2.0f * xv);
  float t  = (e - 1.0f) * __builtin_amdgcn_rcpf(e + 1.0f);
  float uf = (t + 1.0f) * 5.5f;            // /h
  int   c  = (int)uf;  c = c > 10 ? 10 : c;
  float u  = uf - (float)c;
  float u2 = u * u, u3 = u2 * u, om = 1.0f - u;
  float w0 = om * om * om * (1.0f / 6.0f);
  float w1 = (3.0f * u3 - 6.0f * u2 + 4.0f) * (1.0f / 6.0f);
  float w2 = (-3.0f * u3 + 3.0f * u2 + 3.0f * u + 1.0f) * (1.0f / 6.0f);
  float w3 = u3 * (1.0f / 6.0f);
  uint32_t p01 = f2bf(w0) | (f2bf(w1) << 16);
  uint32_t p23 = f2bf(w2) | (f2bf(w3) << 16);
  uint64_t W = (uint64_t)p01 | ((uint64_t)p23 << 32);
  int d = c - 3;                            // slot of w0, in [-3, 7]
  uint64_t lo = (d < 0) ? (W >> ((-d) * 16))
              : ((d < 4) ? (W << (d * 16)) : 0ull);
  uint64_t hi = (d <= 0) ? 0ull
              : ((d < 4) ? (W >> ((4 - d) * 16)) : (W << ((d - 4) * 16)));
  o[0] = (uint32_t)lo; o[1] = (uint32_t)(lo >> 32);
  o[2] = (uint32_t)hi; o[3] = (uint32_t)(hi >> 32);
}

// ---------------- coeff cast: [512][512][8] fp32 -> bf16 (== B^T[512][4096]) --
__global__ __launch_bounds__(256) void cvt_kernel(const float* __restrict__ c,
                                                  __hip_bfloat16* __restrict__ Bt,
                                                  int total8) {
  int idx = blockIdx.x * 256 + threadIdx.x;
  if (idx >= total8) return;
  const float4* cp = reinterpret_cast<const float4*>(c) + (size_t)idx * 2;
  float4 a = cp[0], b = cp[1];
  union { unsigned short us[8]; int4 v; } pk;
  pk.us[0] = (unsigned short)f2bf(a.x); pk.us[1] = (unsigned short)f2bf(a.y);
  pk.us[2] = (unsigned short)f2bf(a.z); pk.us[3] = (unsigned short)f2bf(a.w);
  pk.us[4] = (unsigned short)f2bf(b.x); pk.us[5] = (unsigned short)f2bf(b.y);
  pk.us[6] = (unsigned short)f2bf(b.z); pk.us[7] = (unsigned short)f2bf(b.w);
  reinterpret_cast<int4*>(Bt)[idx] = pk.v;
}

// ---------------- fused GEMM: C[m,n] = sum_k basisA[m,k]*Bt[n,k] -------------
// 512 thr = 8 waves: kgrp = wid>>2 (K-half), 2x2 waves of 64x64 per group.
__global__ __launch_bounds__(512) void gemm_kernel(
    const float* __restrict__ x,            // [8192][512]
    const __hip_bfloat16* __restrict__ Bt,  // [512][4096]
    float* __restrict__ C) {                // [8192][512]
  __shared__ char lds[2 * GRP_LDS];         // 128 KB

  const int tid   = threadIdx.x;
  const int wid   = tid >> 6;               // 0..7
  const int lane  = tid & 63;
  const int quad  = lane >> 4;
  const int l16   = lane & 15;
  const int kgrp  = wid >> 2;               // 0..1: K-half
  const int w2    = wid & 3;
  const int waveM = w2 >> 1, waveN = w2 & 1;
  const int tg    = tid & 255;              // thread-in-group

  // XCD decode: each XCD owns 8 M-stripes x all 4 N-tiles; Bt (4MB) and the
  // XCD's x-stripe (2MB) stay L2-resident, streamed once from HBM/L3.
  const int b  = blockIdx.x;
  const int q  = b >> 3;                    // 0..31
  const int mt = (b & 7) * 8 + (q >> 2);    // 0..63
  const int nt = q & 3;                     // 0..3
  const int m0 = mt * BM;
  const int n0 = nt * BN;

  char* grp = lds + kgrp * GRP_LDS;

  // ---- A staging via on-the-fly basis: thread owns row rA, chunks c0..c0+3.
  // LDS layout (R7): row-major 128B lines, chunk p = c ^ (row&7) (XOR swizzle).
  const int rA = tg >> 1;                   // 0..127
  const int c0 = (tg & 1) * 4;              // 0 or 4
  // x address: i = kgrp*256 + it*8 + c  (4 consecutive i per thread -> f4 load)
  const float* xp = x + (size_t)(m0 + rA) * N_DIM + (kgrp * 256 + c0);
  uint32_t aW[4];
#pragma unroll
  for (int j = 0; j < 4; ++j) {
    int p = (c0 + j) ^ (rA & 7);
    aW[j] = (uint32_t)(rA * 128 + p * 16);
  }

  // ---- B staging (R7 verbatim): slot s -> (row, phys chunk p); src cc=p^(row&7)
  uint32_t bGlob[4], sOffB[4];
#pragma unroll
  for (int t = 0; t < 4; ++t) {
    int s = t * 256 + tg, row = s >> 3, p = s & 7, cc = p ^ (row & 7);
    sOffB[t] = (uint32_t)s * 16u;
    bGlob[t] = (uint32_t)(n0 + row) * K_DIM + (uint32_t)cc * 8u
             + (uint32_t)kgrp * 2048u;
  }

  // fragment read offsets within a buffer (A at +0, B at +16KB)
  uint32_t aOff[2][4], bOff[2][4];
#pragma unroll
  for (int kk = 0; kk < 2; ++kk) {
    int c = kk * 4 + quad;
#pragma unroll
    for (int mi = 0; mi < 4; ++mi) {
      int row = waveM * 64 + mi * 16 + l16;
      aOff[kk][mi] = (uint32_t)(row * 8 + (c ^ (row & 7))) * 16u;
    }
#pragma unroll
    for (int ni = 0; ni < 4; ++ni) {
      int row = waveN * 64 + ni * 16 + l16;
      bOff[kk][ni] = 16384u + (uint32_t)(row * 8 + (c ^ (row & 7))) * 16u;
    }
  }

  f32x4 acc[4][4];
#pragma unroll
  for (int mi = 0; mi < 4; ++mi)
#pragma unroll
    for (int ni = 0; ni < 4; ++ni)
      acc[mi][ni] = (f32x4){0.f, 0.f, 0.f, 0.f};

  // ---- prologue: x(0) serial, stage tile 0 into buffer 0, prefetch x(1)
  float4 xn = *reinterpret_cast<const float4*>(xp);
  {
    char* buf0 = grp;
#pragma unroll
    for (int j = 0; j < 4; ++j) {
      uint32_t o[4];
      basis_slots(j == 0 ? xn.x : j == 1 ? xn.y : j == 2 ? xn.z : xn.w, o);
      *reinterpret_cast<int4*>(buf0 + aW[j]) = make_int4(o[0], o[1], o[2], o[3]);
    }
#pragma unroll
    for (int t = 0; t < 4; ++t)
      gload_lds16(Bt + bGlob[t], buf0 + 16384 + sOffB[t]);
  }
  xn = *reinterpret_cast<const float4*>(xp + 8);   // x(1)

  for (int it = 0; it < NT_HALF; ++it) {
    const int cur = it & 1;
    char* bufc = grp + cur * BUF_HALF;
    __syncthreads();                        // tile it staged (lgkm+vm drained)
    if (it + 1 < NT_HALF) {                 // stage it+1 under compute of it
      char* bufn = grp + (1 - cur) * BUF_HALF;
      // issue x(it+2) early (1-iter cover), consume xn = x(it+1)
      int nx = it + 2 < NT_HALF ? it + 2 : NT_HALF - 1;
      float4 xt = *reinterpret_cast<const float4*>(xp + (size_t)nx * 8);
#pragma unroll
      for (int j = 0; j < 4; ++j) {
        uint32_t o[4];
        basis_slots(j == 0 ? xn.x : j == 1 ? xn.y : j == 2 ? xn.z : xn.w, o);
        *reinterpret_cast<int4*>(bufn + aW[j]) =
            make_int4(o[0], o[1], o[2], o[3]);
      }
      uint32_t kt = (uint32_t)(it + 1) * BK;
#pragma unroll
      for (int t = 0; t < 4; ++t)
        gload_lds16(Bt + bGlob[t] + kt, bufn + 16384 + sOffB[t]);
      xn = xt;
    }
#pragma unroll
    for (int kk = 0; kk < 2; ++kk) {
      short8 af[4], bf[4];
#pragma unroll
      for (int mi = 0; mi < 4; ++mi)
        af[mi] = *reinterpret_cast<const short8*>(bufc + aOff[kk][mi]);
#pragma unroll
      for (int ni = 0; ni < 4; ++ni)
        bf[ni] = *reinterpret_cast<const short8*>(bufc + bOff[kk][ni]);
#pragma unroll
      for (int mi = 0; mi < 4; ++mi)
#pragma unroll
        for (int ni = 0; ni < 4; ++ni)
          acc[mi][ni] = __builtin_amdgcn_mfma_f32_16x16x32_bf16(
              af[mi], bf[ni], acc[mi][ni], 0, 0, 0);
    }
  }

  // split-K pair reduction: group 1 parks partials, group 0 sums + stores
  __syncthreads();
  if (kgrp == 1) {
#pragma unroll
    for (int mi = 0; mi < 4; ++mi)
#pragma unroll
      for (int ni = 0; ni < 4; ++ni) {
        int f = mi * 4 + ni;
        *reinterpret_cast<f32x4*>(lds + w2 * 16384 + f * 1024 + lane * 16) =
            acc[mi][ni];
      }
  }
  __syncthreads();
  if (kgrp == 0) {
#pragma unroll
    for (int mi = 0; mi < 4; ++mi) {
#pragma unroll
      for (int ni = 0; ni < 4; ++ni) {
        int f = mi * 4 + ni;
        f32x4 other = *reinterpret_cast<f32x4*>(
            lds + w2 * 16384 + f * 1024 + lane * 16);
        f32x4 s = acc[mi][ni] + other;
        int col = n0 + waveN * 64 + ni * 16 + l16;
#pragma unroll
        for (int r = 0; r < 4; ++r) {
          int row = m0 + waveM * 64 + mi * 16 + quad * 4 + r;
          C[(size_t)row * N_DIM + col] = s[r];   // m89/m91 C/D layout
        }
      }
    }
  }
}

extern "C" void kernel_launch(void* const* d_in, const int* in_sizes, int n_in,
                              void* d_out, int out_size, void* d_ws, size_t ws_size,
                              hipStream_t stream) {
  const float* x    = (const float*)d_in[0];   // [8192,512]
  const float* coef = (const float*)d_in[1];   // [512,512,8]
  float* out = (float*)d_out;                  // [8192,512]

  __hip_bfloat16* Bt = (__hip_bfloat16*)d_ws;  // 4 MB (only ws use now)

  const int total8 = N_DIM * K_DIM / 8;        // 262144
  cvt_kernel<<<(total8 + 255) / 256, 256, 0, stream>>>(coef, Bt, total8);

  gemm_kernel<<<(M_TOTAL / BM) * (N_DIM / BN), 512, 0, stream>>>(x, Bt, out);
}